// Round 6
// baseline (72675.659 us; speedup 1.0000x reference)
//
#include <hip/hip_runtime.h>
#include <math.h>

#define Bz   32
#define Hz   512
#define Vz   32000
#define Tz   128
#define BHz  (Bz*Hz)                 // 16384
#define TVz  ((size_t)Tz*(size_t)Vz)
#define BTVz ((size_t)Bz*TVz)
#define GP   500                     // proj blocks
#define VB   64                      // vocab rows per proj block

// workspace byte offsets
#define WS_H    0        // float[2 par][2 layer][32][512] = 262144 B
#define WS_C    262144   // float[2 layer][32][512]        = 131072 B
#define WS_SUM  393216   // float[2 set][64][32]           = 16384 B
#define WS_MAX  409600   // ull  [2 set][64][32]           = 32768 B

// k_lstm dynamic LDS
#define LL_XS   0
#define LL_HS   65536
#define LL_GL   131072   // float[16][32]
#define LL_AXM  133120   // ull[8][32]
#define LL_TOK  135168   // int[32]
#define LSTM_LDS 135296

// k_proj dynamic LDS
#define LP_HS   0        // float[32][512] plain
#define LP_LG   65536    // float[32][68]
#define LP_SP   74240    // float[4][8][32]  (also AX overlay in fix phase)
#define LP_PM   78336    // ull[8][32]
#define LP_PS   80384    // float[8][32]
#define LP_LZ   81408    // float[32]
#define PROJ_LDS 81536   // <= 80 KB -> 2 blocks/CU

typedef unsigned long long ull;
typedef float f32x4 __attribute__((ext_vector_type(4)));
typedef float f32x2 __attribute__((ext_vector_type(2)));

__device__ __forceinline__ float sigmf(float x) { return 1.0f / (1.0f + expf(-x)); }

__device__ __forceinline__ ull packlm(float x, int v) {
  unsigned u = __float_as_uint(x);
  u = (u & 0x80000000u) ? ~u : (u | 0x80000000u);   // order-preserving map
  return ((ull)u << 32) | (unsigned)(Vz - 1 - v);   // lower v wins ties (np.argmax first-max)
}

//============================ init ==========================================
__global__ void rnn_init(const float* __restrict__ enc, float* __restrict__ ws) {
  int i = blockIdx.x * blockDim.x + threadIdx.x;    // 64*512 = 32768
  float* h0 = (float*)((char*)ws + WS_H);           // parity-0 h = enc ([L][B][H] matches)
  float* c  = (float*)((char*)ws + WS_C);
  float* sums = (float*)((char*)ws + WS_SUM);
  ull*   maxes = (ull*)((char*)ws + WS_MAX);
  if (i < 16384) {
    *(f32x2*)(h0 + 2*i) = *(const f32x2*)(enc + 2*i);
    f32x2 z; z.x = 0.f; z.y = 0.f;
    *(f32x2*)(c + 2*i) = z;
  }
  if (i < 4096) sums[i] = 0.f;
  if (i < 4096) maxes[i] = 0ull;
}

//============================ LSTM layer kernel =============================
// grid 128 blocks x 512 threads; block bid owns hidden units bid*4..bid*4+3.
template<int LAYER, bool FIRST>
__global__ __launch_bounds__(512, 2) void k_lstm(
    const float* __restrict__ emb,
    const float* __restrict__ Wl_ih, const float* __restrict__ Wl_hh,
    const float* __restrict__ bl_ih, const float* __restrict__ bl_hh,
    const float* __restrict__ xsrc,   // LAYER==1: fresh h0 (parity-new)
    const float* __restrict__ hold,   // h(parity-old, LAYER)
    float* __restrict__ hnew,         // h(parity-new, LAYER)
    float* __restrict__ cbuf,         // c + LAYER*BHz
    const ull* __restrict__ mprev,    // LAYER==0 && !FIRST: token max-buckets
    float* __restrict__ zs, ull* __restrict__ zm)   // LAYER==1: zero cur-step buckets
{
  extern __shared__ char sm[];
  float* XS  = (float*)(sm + LL_XS);
  float* HS  = (float*)(sm + LL_HS);
  float* GL  = (float*)(sm + LL_GL);
  ull*   AXM = (ull*)(sm + LL_AXM);
  int*   TOK = (int*)(sm + LL_TOK);
  const int tid = threadIdx.x, bid = blockIdx.x;

  if (LAYER == 1 && tid < 16) { zs[bid*16 + tid] = 0.f; zm[bid*16 + tid] = 0ull; }

  if (LAYER == 0) {
    if (FIRST) {
      if (tid < 32) TOK[tid] = 1;    // SOS
    } else {
      if (tid < 256) {
        int b = tid & 31, g = tid >> 5;
        ull m = 0ull;
        #pragma unroll
        for (int u = 0; u < 8; ++u) { ull x = mprev[(g*8 + u)*32 + b]; m = x > m ? x : m; }
        AXM[g*32 + b] = m;
      }
      __syncthreads();
      if (tid < 32) {
        ull m = 0ull;
        #pragma unroll
        for (int g = 0; g < 8; ++g) { ull x = AXM[g*32 + tid]; m = x > m ? x : m; }
        TOK[tid] = (Vz - 1) - (int)(unsigned)(m & 0xffffffffull);
      }
    }
    __syncthreads();
  }

  // stage x tile (swizzled [32][512])
  if (LAYER == 0) {
    #pragma unroll
    for (int it = 0; it < 16; ++it) {
      int f = ((it << 9) + tid) << 1;           // step-2 floats
      int b = f >> 9, k = f & 511;
      const float* er = emb + (size_t)TOK[b] * Hz + k;
      int o = (b << 9) + (k ^ ((b & 15) << 2));
      XS[o]     = fmaxf(er[0], 0.f);
      XS[o + 1] = fmaxf(er[1], 0.f);
    }
  } else {
    #pragma unroll
    for (int it = 0; it < 8; ++it) {
      int f = ((it << 9) + tid) << 2;
      int b = f >> 9, k = f & 511;
      *(f32x4*)(XS + (b << 9) + (k ^ ((b & 15) << 2))) = *(const f32x4*)(xsrc + f);
    }
  }
  // stage h tile
  #pragma unroll
  for (int it = 0; it < 8; ++it) {
    int f = ((it << 9) + tid) << 2;
    int b = f >> 9, k = f & 511;
    *(f32x4*)(HS + (b << 9) + (k ^ ((b & 15) << 2))) = *(const f32x4*)(hold + f);
  }
  __syncthreads();

  // compute: thread (r = tid>>5, b = tid&31) -> gate-row r (= gate*4+hl), batch b
  {
    const int r = tid >> 5, b = tid & 31;
    const int gate = r >> 2, hl = r & 3;
    const int j = gate * Hz + (bid << 2) + hl;
    const float* wi = Wl_ih + (size_t)j * Hz;
    const float* wh = Wl_hh + (size_t)j * Hz;
    const int swz = (b & 15) << 2;
    const float* xb = XS + (b << 9);
    const float* hb = HS + (b << 9);
    float acc = bl_ih[j] + bl_hh[j];
    #pragma unroll 4
    for (int k = 0; k < Hz; k += 4) {
      f32x4 x4 = *(const f32x4*)(xb + (k ^ swz));
      f32x4 h4 = *(const f32x4*)(hb + (k ^ swz));
      f32x4 wi4 = *(const f32x4*)(wi + k);
      f32x4 wh4 = *(const f32x4*)(wh + k);
      acc += x4.x*wi4.x + x4.y*wi4.y + x4.z*wi4.z + x4.w*wi4.w
           + h4.x*wh4.x + h4.y*wh4.y + h4.z*wh4.z + h4.w*wh4.w;
    }
    GL[r*32 + b] = acc;
  }
  __syncthreads();
  if (tid < 128) {
    int hl = tid >> 5, b = tid & 31;
    float gi = GL[(0  + hl)*32 + b];
    float gf = GL[(4  + hl)*32 + b];
    float gg = GL[(8  + hl)*32 + b];
    float go = GL[(12 + hl)*32 + b];
    int ci = (b << 9) + (bid << 2) + hl;
    float c_old = cbuf[ci];
    float cn = sigmf(gf)*c_old + sigmf(gi)*tanhf(gg);
    cbuf[ci] = cn;
    hnew[ci] = sigmf(go)*tanhf(cn);
  }
}

//============================ projection kernel =============================
// grid 500 blocks x 256 threads; block bid owns vocab rows bid*64..+63.
template<bool FIRST>
__global__ __launch_bounds__(256, 2) void k_proj(
    const float* __restrict__ Wout, const float* __restrict__ bout,
    const float* __restrict__ h2,     // h(parity-new, layer 1)
    float* __restrict__ out, int t,
    const float* __restrict__ sprev,  // sum-buckets of step t-1 (logZ for fix)
    float* __restrict__ scur, ull* __restrict__ mcur)
{
  extern __shared__ char sm[];
  float* HS = (float*)(sm + LP_HS);
  float* LG = (float*)(sm + LP_LG);
  float* SP = (float*)(sm + LP_SP);
  ull*   PM = (ull*)(sm + LP_PM);
  float* PS = (float*)(sm + LP_PS);
  float* LZ = (float*)(sm + LP_LZ);
  const int tid = threadIdx.x, bid = blockIdx.x;
  const int v0 = bid * VB;
  const int b = tid & 31, kq = tid >> 5;

  // stage h2 (plain [32][512]; matvec reads are wave-broadcast -> conflict-free)
  #pragma unroll
  for (int it = 0; it < 16; ++it) {
    int f = ((it << 8) + tid) << 2;
    *(f32x4*)(HS + f) = *(const f32x4*)(h2 + f);
  }

  // fix previous step's raw logits -> logp
  if (!FIRST) {
    {
      int g = tid >> 5;
      float s = 0.f;
      #pragma unroll
      for (int u = 0; u < 8; ++u) s += sprev[(g*8 + u)*32 + b];
      SP[g*32 + b] = s;
    }
    __syncthreads();
    if (tid < 32) {
      float s = 0.f;
      #pragma unroll
      for (int g = 0; g < 8; ++g) s += SP[g*32 + tid];
      LZ[tid] = logf(s);
    }
    __syncthreads();
    {
      int q = tid & 7, b2 = tid >> 3;
      float lz = LZ[b2];
      size_t o = (size_t)b2 * TVz + (size_t)(t - 1) * Vz + v0 + q*8;
      f32x4 a0 = *(const f32x4*)(out + o);
      f32x4 a1 = *(const f32x4*)(out + o + 4);
      a0 -= lz; a1 -= lz;
      __builtin_nontemporal_store(a0, (f32x4*)(out + o));
      __builtin_nontemporal_store(a1, (f32x4*)(out + o + 4));
    }
  }
  __syncthreads();

  // per-thread h chunk: 64 floats (kq*64..)
  f32x4 hr[16];
  #pragma unroll
  for (int i = 0; i < 16; ++i)
    hr[i] = *(const f32x4*)(HS + (b << 9) + (kq << 6) + (i << 2));

  const int vi = kq;           // accumulate-phase identity
  float m_r = -3.0e38f; int argv_r = 0; float s_r = 0.f;

  for (int g = 0; g < 8; ++g) {
    float p[8];
    #pragma unroll
    for (int v8 = 0; v8 < 8; ++v8) {
      const float* wr = Wout + (size_t)(v0 + g*8 + v8) * Hz + (kq << 6);
      f32x4 a = (f32x4)0.f;
      #pragma unroll
      for (int i = 0; i < 16; ++i) a += (*(const f32x4*)(wr + (i << 2))) * hr[i];
      p[v8] = (a.x + a.y) + (a.z + a.w);
    }
    #pragma unroll
    for (int v8 = 0; v8 < 8; ++v8) {
      float p2 = p[v8] + __shfl_xor(p[v8], 32);   // combine kq pair within wave
      if ((kq & 1) == 0) SP[((kq >> 1)*8 + v8)*32 + b] = p2;
    }
    __syncthreads();
    {
      float l = SP[(0*8 + vi)*32 + b] + SP[(1*8 + vi)*32 + b]
              + SP[(2*8 + vi)*32 + b] + SP[(3*8 + vi)*32 + b]
              + bout[v0 + g*8 + vi];
      LG[b*68 + g*8 + vi] = l;
      float e = expf(l);                 // offset-0 softmax: logits O(1), safe
      s_r += e;
      if (l > m_r) { m_r = l; argv_r = g*8 + vi; }
    }
    __syncthreads();
  }
  PM[vi*32 + b] = packlm(m_r, v0 + argv_r);
  PS[vi*32 + b] = s_r;
  __syncthreads();
  if (tid < 32) {
    ull m = 0ull; float s = 0.f;
    #pragma unroll
    for (int u = 0; u < 8; ++u) {
      ull x = PM[u*32 + tid]; m = x > m ? x : m;
      s += PS[u*32 + tid];
    }
    atomicAdd(&scur[(bid & 63)*32 + tid], s);
    atomicMax(&mcur[(bid & 63)*32 + tid], m);
  }
  // store raw logits for step t
  {
    int q = tid & 7, b2 = tid >> 3;
    size_t o = (size_t)b2 * TVz + (size_t)t * Vz + v0 + q*8;
    f32x4 a0 = *(const f32x4*)(LG + b2*68 + q*8);
    f32x4 a1 = *(const f32x4*)(LG + b2*68 + q*8 + 4);
    __builtin_nontemporal_store(a0, (f32x4*)(out + o));
    __builtin_nontemporal_store(a1, (f32x4*)(out + o + 4));
  }
}

//============================ final fix + hc copy ===========================
__global__ __launch_bounds__(256) void k_fixlast(
    float* __restrict__ out, const float* __restrict__ sprev)
{
  __shared__ float AX[8*32];
  __shared__ float LZ[32];
  const int tid = threadIdx.x, bid = blockIdx.x;
  const int v0 = bid * VB;
  int b = tid & 31, g = tid >> 5;
  float s = 0.f;
  #pragma unroll
  for (int u = 0; u < 8; ++u) s += sprev[(g*8 + u)*32 + b];
  AX[g*32 + b] = s;
  __syncthreads();
  if (tid < 32) {
    float ss = 0.f;
    #pragma unroll
    for (int gg = 0; gg < 8; ++gg) ss += AX[gg*32 + tid];
    LZ[tid] = logf(ss);
  }
  __syncthreads();
  int q = tid & 7, b2 = tid >> 3;
  float lz = LZ[b2];
  size_t o = (size_t)b2 * TVz + (size_t)(Tz - 1) * Vz + v0 + q*8;
  f32x4 a0 = *(const f32x4*)(out + o);
  f32x4 a1 = *(const f32x4*)(out + o + 4);
  a0 -= lz; a1 -= lz;
  __builtin_nontemporal_store(a0, (f32x4*)(out + o));
  __builtin_nontemporal_store(a1, (f32x4*)(out + o + 4));
}

__global__ void k_hc(const float* __restrict__ h0, const float* __restrict__ c,
                     float* __restrict__ out) {
  int i = blockIdx.x * blockDim.x + threadIdx.x;   // 32 blocks x 256 = 8192
  int f = i << 2;                                  // 32768 floats each
  *(f32x4*)(out + BTVz + f)               = *(const f32x4*)(h0 + f);
  *(f32x4*)(out + BTVz + 2*BHz + f)       = *(const f32x4*)(c + f);
}

//============================ host ==========================================
extern "C" void kernel_launch(void* const* d_in, const int* in_sizes, int n_in,
                              void* d_out, int out_size, void* d_ws, size_t ws_size,
                              hipStream_t stream) {
  (void)in_sizes; (void)n_in; (void)out_size; (void)ws_size;
  const float* enc  = (const float*)d_in[0];
  const float* emb  = (const float*)d_in[1];
  const float* Wih  = (const float*)d_in[2];
  const float* Whh  = (const float*)d_in[3];
  const float* bih  = (const float*)d_in[4];
  const float* bhh  = (const float*)d_in[5];
  const float* Wout = (const float*)d_in[6];
  const float* bout = (const float*)d_in[7];
  float* out = (float*)d_out;

  float* h     = (float*)((char*)d_ws + WS_H);    // [2][2][32][512]
  float* c     = (float*)((char*)d_ws + WS_C);    // [2][32][512]
  float* sums  = (float*)((char*)d_ws + WS_SUM);  // [2][64][32]
  ull*   maxes = (ull*)((char*)d_ws + WS_MAX);    // [2][64][32]

  (void)hipFuncSetAttribute((const void*)k_lstm<0,true>,
      hipFuncAttributeMaxDynamicSharedMemorySize, LSTM_LDS);
  (void)hipFuncSetAttribute((const void*)k_lstm<0,false>,
      hipFuncAttributeMaxDynamicSharedMemorySize, LSTM_LDS);
  (void)hipFuncSetAttribute((const void*)k_lstm<1,false>,
      hipFuncAttributeMaxDynamicSharedMemorySize, LSTM_LDS);
  (void)hipFuncSetAttribute((const void*)k_proj<true>,
      hipFuncAttributeMaxDynamicSharedMemorySize, PROJ_LDS);
  (void)hipFuncSetAttribute((const void*)k_proj<false>,
      hipFuncAttributeMaxDynamicSharedMemorySize, PROJ_LDS);

  rnn_init<<<64, 512, 0, stream>>>(enc, (float*)d_ws);

  const size_t W1 = (size_t)2048 * Hz;   // layer-1 weight offset

  for (int t = 0; t < Tz; ++t) {
    const int po = t & 1, pn = (t + 1) & 1;
    const float* h0_old = h + (po*2 + 0) * BHz;
    float*       h0_new = h + (pn*2 + 0) * BHz;
    const float* h1_old = h + (po*2 + 1) * BHz;
    float*       h1_new = h + (pn*2 + 1) * BHz;
    const int sp = (t + 1) & 1;          // bucket set of step t-1
    const int sc = t & 1;                // bucket set of step t

    if (t == 0)
      k_lstm<0,true><<<128, 512, LSTM_LDS, stream>>>(
          emb, Wih, Whh, bih, bhh, nullptr, h0_old, h0_new, c,
          nullptr, nullptr, nullptr);
    else
      k_lstm<0,false><<<128, 512, LSTM_LDS, stream>>>(
          emb, Wih, Whh, bih, bhh, nullptr, h0_old, h0_new, c,
          maxes + sp*2048, nullptr, nullptr);

    k_lstm<1,false><<<128, 512, LSTM_LDS, stream>>>(
        emb, Wih + W1, Whh + W1, bih + 2048, bhh + 2048,
        h0_new, h1_old, h1_new, c + BHz,
        nullptr, sums + sc*2048, maxes + sc*2048);

    if (t == 0)
      k_proj<true><<<GP, 256, PROJ_LDS, stream>>>(
          Wout, bout, h1_new, out, t, nullptr, sums, maxes);
    else
      k_proj<false><<<GP, 256, PROJ_LDS, stream>>>(
          Wout, bout, h1_new, out, t,
          sums + sp*2048, sums + sc*2048, maxes + sc*2048);
  }

  k_fixlast<<<GP, 256, 0, stream>>>(out, sums + ((Tz - 1) & 1)*2048);
  k_hc<<<32, 256, 0, stream>>>(h, c, out);   // final parity is 0
}

// Round 7
// 16874.849 us; speedup vs baseline: 4.3067x; 4.3067x over previous
//
#include <hip/hip_runtime.h>
#include <math.h>

#define Gz   250
#define NTz  512
#define Bz   32
#define Hz   512
#define Vz   32000
#define Tz   128
#define VBz  128
#define BHz  (Bz*Hz)
#define LBHz (2*BHz)
#define BTVz ((size_t)Bz*(size_t)Tz*(size_t)Vz)

// workspace byte offsets
#define WS_BAR  0         // unsigned[512]: grp[i] at [i*32], master at [256], gen at [257]
#define WS_ASUM 2048      // float[64][32]
#define WS_AMAX 10240     // ull[64][32]
#define WS_H    26624     // float[2 parity][2 layer][32][512]
#define WS_TIME 288768    // ull[4]: w12, x12, w3, x3 (realtime ticks)

// LDS byte offsets (dynamic)
#define L_HSA    0         // float[32][512] (swizzled for LSTM; plain for P3 overlay)
#define L_HSB    65536     // float[32][512] swizzled
#define L_LOGITS 131072    // float[32*129]
#define L_SPART  131072    // overlay: float[16*32*8] (clobbers logits AFTER write_logp)
#define L_PMAX   147584    // ull[16*32]
#define L_PSUM   151680    // float[16*32]
#define L_REDM   153728    // ull[8*32]
#define L_REDS   155776    // float[8*32]
#define L_BIAS   156800    // float[16]
#define L_LOGZ   156864    // float[32]
#define L_TOK    156992    // int[32]
#define L_C      157120    // float[2][4][32]
#define L_TOTAL  158144

typedef unsigned long long ull;
typedef float f32x4 __attribute__((ext_vector_type(4)));
typedef float f32x2 __attribute__((ext_vector_type(2)));

__device__ __forceinline__ float sigmf(float x) { return 1.0f / (1.0f + expf(-x)); }
__device__ __forceinline__ ull rtclk() { return __builtin_amdgcn_s_memrealtime(); }

__device__ __forceinline__ ull bp8(const float* p) {   // coherent 8B load (MALL-direct)
  return __hip_atomic_load((const ull*)p, __ATOMIC_RELAXED, __HIP_MEMORY_SCOPE_AGENT);
}
__device__ __forceinline__ void cstore(float* p, float v) {  // MALL-direct 4B store
  __hip_atomic_store(p, v, __ATOMIC_RELAXED, __HIP_MEMORY_SCOPE_AGENT);
}
__device__ __forceinline__ ull packlm(float x, int v) {
  unsigned u = __float_as_uint(x);
  u = (u & 0x80000000u) ? ~u : (u | 0x80000000u);
  return ((ull)u << 32) | (unsigned)(Vz - 1 - v);   // lower v wins ties (np.argmax first-max)
}
// swizzled float index into [32][512] LDS tile (LSTM tiles)
__device__ __forceinline__ int hoff(int b, int k) { return (b << 9) + (k ^ ((b & 15) << 2)); }

// ALL-RELAXED grid barrier: no release/acquire -> no buffer_wbl2/buffer_inv.
// Ordering enforced with explicit s_waitcnt vmcnt(0) at the two publish edges.
// All cross-block data uses sc1 (MALL-direct) accesses, so no L2 flush is needed.
// Block 0 accumulates work/wait realtime ticks (timing instrumentation).
__device__ __forceinline__ void grid_barrier_rt(unsigned* bar, int bid,
                                                ull& wacc, ull& xacc, ull tA) {
  __syncthreads();
  if (threadIdx.x == 0) {
    ull tB = 0;
    if (bid == 0) { tB = rtclk(); wacc += tB - tA; }
    unsigned* gen = bar + 257;
    unsigned g = __hip_atomic_load(gen, __ATOMIC_RELAXED, __HIP_MEMORY_SCOPE_AGENT);
    const int gi = bid & 7;
    const unsigned gsz = (unsigned)(Gz >> 3) + (((unsigned)gi < (Gz & 7u)) ? 1u : 0u);
    unsigned prev = __hip_atomic_fetch_add(&bar[gi * 32], 1u, __ATOMIC_RELAXED, __HIP_MEMORY_SCOPE_AGENT);
    if (prev == gsz - 1u) {
      __hip_atomic_store(&bar[gi * 32], 0u, __ATOMIC_RELAXED, __HIP_MEMORY_SCOPE_AGENT);
      asm volatile("s_waitcnt vmcnt(0)" ::: "memory");   // grp reset acked before master bump
      unsigned pm = __hip_atomic_fetch_add(&bar[256], 1u, __ATOMIC_RELAXED, __HIP_MEMORY_SCOPE_AGENT);
      if (pm == 7u) {
        __hip_atomic_store(&bar[256], 0u, __ATOMIC_RELAXED, __HIP_MEMORY_SCOPE_AGENT);
        asm volatile("s_waitcnt vmcnt(0)" ::: "memory"); // master reset acked before gen flip
        __hip_atomic_store(gen, g + 1u, __ATOMIC_RELAXED, __HIP_MEMORY_SCOPE_AGENT);
      }
    }
    while (__hip_atomic_load(gen, __ATOMIC_RELAXED, __HIP_MEMORY_SCOPE_AGENT) == g)
      __builtin_amdgcn_s_sleep(1);
    if (bid == 0) xacc += rtclk() - tB;
  }
  __syncthreads();
}

// stage [32][512] floats from coherent global into swizzled LDS tile
__device__ __forceinline__ void stage_rows(const float* __restrict__ src, float* lds, int tid) {
  #pragma unroll
  for (int it = 0; it < 16; ++it) {
    int f = (it * NTz + tid) << 1;
    int b = f >> 9, k = f & 511;
    ull v = bp8(src + f);
    *(ull*)(lds + hoff(b, k)) = v;
  }
}
// stage [32][512] floats into PLAIN LDS tile (P3: broadcast-pattern reads, no swizzle)
__device__ __forceinline__ void stage_plain(const float* __restrict__ src, float* lds, int tid) {
  #pragma unroll
  for (int it = 0; it < 16; ++it) {
    int f = (it * NTz + tid) << 1;
    ull v = bp8(src + f);
    *(ull*)(lds + f) = v;
  }
}

// one LSTM layer: 512 threads = 2 rowgroups x 8 kq x 32 b. Each thread: 8 gate-rows
// over a 64-wide k slice. x/h from swizzled LDS (or emb), W normal cached loads.
template<bool X_FROM_EMB>
__device__ __forceinline__ void lstm_phase(
    int tid, int hblk,
    const float* __restrict__ emb, const int* s_tok_,
    const float* xlds, const float* hlds,
    const float* __restrict__ Wih, const float* __restrict__ Whh,
    const float* __restrict__ bih, const float* __restrict__ bhh,
    float* s_part_, float* s_bias_, float* c_l,
    float* hdst)
{
  if (tid < 16) {
    int gate = tid >> 2, hl = tid & 3;
    int j = gate * Hz + (hblk << 2) + hl;
    s_bias_[tid] = bih[j] + bhh[j];
  }
  const int b = tid & 31, kq = (tid >> 5) & 7, rp = tid >> 8;
  const int k0 = kq * 64;
  const int swz = (b & 15) << 2;

  const float* wiP[8]; const float* whP[8];
  #pragma unroll
  for (int r = 0; r < 8; ++r) {
    int row = rp * 8 + r; int gate = row >> 2, hl = row & 3;
    size_t j = (size_t)(gate * Hz + (hblk << 2) + hl) * Hz + k0;
    wiP[r] = Wih + j; whP[r] = Whh + j;
  }
  const float* xbase; const float* hbase = hlds + (b << 9);
  if (X_FROM_EMB) xbase = emb + (size_t)s_tok_[b] * Hz + k0;
  else            xbase = xlds + (b << 9);

  float acc[8];
  #pragma unroll
  for (int r = 0; r < 8; ++r) acc[r] = 0.f;

  #pragma unroll 2
  for (int c = 0; c < 64; c += 4) {
    float x0, x1, x2, x3;
    if (X_FROM_EMB) {
      float4 xv = *(const float4*)(xbase + c);
      x0 = fmaxf(xv.x, 0.f); x1 = fmaxf(xv.y, 0.f);
      x2 = fmaxf(xv.z, 0.f); x3 = fmaxf(xv.w, 0.f);
    } else {
      float4 xv = *(const float4*)(xbase + ((k0 + c) ^ swz));
      x0 = xv.x; x1 = xv.y; x2 = xv.z; x3 = xv.w;
    }
    float4 hv = *(const float4*)(hbase + ((k0 + c) ^ swz));
    #pragma unroll
    for (int r = 0; r < 8; ++r) {
      float4 wiv = *(const float4*)(wiP[r] + c);
      float4 whv = *(const float4*)(whP[r] + c);
      acc[r] += x0 * wiv.x + x1 * wiv.y + x2 * wiv.z + x3 * wiv.w
              + hv.x * whv.x + hv.y * whv.y + hv.z * whv.z + hv.w * whv.w;
    }
  }
  #pragma unroll
  for (int r = 0; r < 8; ++r)
    s_part_[((rp * 8 + r) * 32 + b) * 8 + kq] = acc[r];
  __syncthreads();
  {
    int row = tid >> 5, bb = tid & 31;
    float s = s_bias_[row];
    #pragma unroll
    for (int q = 0; q < 8; ++q) s += s_part_[(row * 32 + bb) * 8 + q];
    s_part_[(row * 32 + bb) * 8] = s;
  }
  __syncthreads();
  if (tid < 128) {
    int hl = tid >> 5, bb = tid & 31;
    float gi = s_part_[((0 * 4 + hl) * 32 + bb) * 8];
    float gf = s_part_[((1 * 4 + hl) * 32 + bb) * 8];
    float gg = s_part_[((2 * 4 + hl) * 32 + bb) * 8];
    float go = s_part_[((3 * 4 + hl) * 32 + bb) * 8];
    float c_old = c_l[hl * 32 + bb];
    float cn = sigmf(gf) * c_old + sigmf(gi) * tanhf(gg);
    c_l[hl * 32 + bb] = cn;
    cstore(hdst + bb * Hz + (hblk << 2) + hl, sigmf(go) * tanhf(cn));
  }
}

__device__ __forceinline__ void tok_reduce(int tid, float* acc_sum, ull* acc_max,
                                           float* redS, ull* redM, float* logZ, int* tok) {
  if (tid < 256) {
    int b = tid & 31, g = tid >> 5;
    float s = 0.f; ull m = 0ull;
    #pragma unroll
    for (int u = 0; u < 8; ++u) {
      int bk = g * 8 + u;
      s += __hip_atomic_load(&acc_sum[bk * Bz + b], __ATOMIC_RELAXED, __HIP_MEMORY_SCOPE_AGENT);
      ull x = __hip_atomic_load(&acc_max[bk * Bz + b], __ATOMIC_RELAXED, __HIP_MEMORY_SCOPE_AGENT);
      m = x > m ? x : m;
    }
    redS[g * Bz + b] = s; redM[g * Bz + b] = m;
  }
  __syncthreads();
  if (tid < 32) {
    float s = 0.f; ull m = 0ull;
    #pragma unroll
    for (int g = 0; g < 8; ++g) {
      s += redS[g * Bz + tid];
      ull x = redM[g * Bz + tid]; m = x > m ? x : m;
    }
    logZ[tid] = logf(s);
    tok[tid] = (Vz - 1) - (int)(unsigned)(m & 0xFFFFFFFFull);
  }
  __syncthreads();
}

__device__ __forceinline__ void write_logp(int tid, int v0, int tstep,
                                           const float* logits_, const float* logZ_, float* out) {
  #pragma unroll
  for (int i = 0; i < 2; ++i) {
    int pos = ((i * NTz) + tid) * 4;      // 0..4095
    int b = pos >> 7, v = pos & 127;
    float lz = logZ_[b];
    f32x4 rr;
    rr.x = logits_[b * 129 + v]     - lz;
    rr.y = logits_[b * 129 + v + 1] - lz;
    rr.z = logits_[b * 129 + v + 2] - lz;
    rr.w = logits_[b * 129 + v + 3] - lz;
    __builtin_nontemporal_store(rr,
        (f32x4*)(out + (size_t)b * ((size_t)Tz * Vz) + (size_t)tstep * Vz + v0 + v));
  }
}

__global__ void rnn_init(const float* __restrict__ enc, float* __restrict__ ws) {
  int i = blockIdx.x * blockDim.x + threadIdx.x;   // 32768 threads
  float* hs = (float*)((char*)ws + WS_H);
  if (i < LBHz) hs[i] = enc[i];
  if (i < 2048) {
    ((float*)((char*)ws + WS_ASUM))[i] = 0.f;
    ((ull*)((char*)ws + WS_AMAX))[i] = 0ull;
  }
  if (i < 512) ((unsigned*)ws)[i] = 0u;
}

// marker kernels: spin for (measured ticks)/16 so per-phase timing shows up as
// rocprof dispatch durations. real_phase_us = marker_dur_us * 16.
template<int IDX>
__global__ void k_marker(const ull* __restrict__ tw) {
  if (threadIdx.x == 0) {
    ull target = tw[IDX] >> 4;
    if (target > 3000000ull) target = 3000000ull;   // 30 ms safety cap
    ull s = rtclk();
    while (rtclk() - s < target) __builtin_amdgcn_s_sleep(32);
  }
}

__global__ __launch_bounds__(NTz, 2) void rnn_decode(
    const float* __restrict__ emb,  const float* __restrict__ Wih,
    const float* __restrict__ Whh,  const float* __restrict__ bih,
    const float* __restrict__ bhh,  const float* __restrict__ Wout,
    const float* __restrict__ bout, float* __restrict__ out,
    float* __restrict__ ws)
{
  extern __shared__ char smem[];
  const int tid = threadIdx.x;
  const int bid = blockIdx.x;

  unsigned* bar  = (unsigned*)ws;
  float* acc_sum = (float*)((char*)ws + WS_ASUM);
  ull*   acc_max = (ull*)((char*)ws + WS_AMAX);
  float* hbufs   = (float*)((char*)ws + WS_H);

  float* hsA    = (float*)(smem + L_HSA);
  float* hsB    = (float*)(smem + L_HSB);
  float* logits = (float*)(smem + L_LOGITS);
  float* s_part = (float*)(smem + L_SPART);
  ull*   pmax   = (ull*)(smem + L_PMAX);
  float* psum   = (float*)(smem + L_PSUM);
  ull*   redM   = (ull*)(smem + L_REDM);
  float* redS   = (float*)(smem + L_REDS);
  float* s_bias = (float*)(smem + L_BIAS);
  float* s_logZ = (float*)(smem + L_LOGZ);
  int*   s_tok  = (int*)(smem + L_TOK);
  float* s_c    = (float*)(smem + L_C);

  const int v0 = bid * VBz;
  if (tid < 256) s_c[tid] = 0.f;
  __syncthreads();

  //---- one-time: this block's W_out slice into registers -------------------
  const int vg = tid >> 4, kq = tid & 15;
  f32x2 w2[4][16];
  float b_r[4];
  #pragma unroll
  for (int r = 0; r < 4; ++r) {
    const float* wrow = Wout + (size_t)(v0 + (vg << 2) + r) * Hz + kq;
    #pragma unroll
    for (int p = 0; p < 16; ++p) {
      const int ca = (p < 8) ? p : p + 8;
      w2[r][p].x = wrow[ca << 4];
      w2[r][p].y = wrow[(ca + 8) << 4];
    }
    b_r[r] = bout[v0 + (vg << 2) + r];
  }

  ull w12 = 0, x12 = 0, w3 = 0, x3 = 0, tA = 0;

  for (int t = 0; t < Tz; ++t) {
    float* h_old = hbufs + (t & 1) * LBHz;
    float* h_new = hbufs + ((t + 1) & 1) * LBHz;

    if (tid == 0 && bid == 0) tA = rtclk();

    //---- P1: stage h0_old; token decode; logp(t-1); LSTM layer 0 ----
    if (bid < 128) stage_rows(h_old, hsA, tid);
    if (t == 0) {
      if (tid < 32) s_tok[tid] = 1;   // SOS
    } else {
      tok_reduce(tid, acc_sum, acc_max, redS, redM, s_logZ, s_tok);
      write_logp(tid, v0, t - 1, logits, s_logZ, out);
    }
    __syncthreads();
    if (bid < 128)
      lstm_phase<true>(tid, bid, emb, s_tok, nullptr, hsA,
                       Wih, Whh, bih, bhh, s_part, s_bias, s_c, h_new);
    grid_barrier_rt(bar, bid, w12, x12, tA);

    if (tid == 0 && bid == 0) tA = rtclk();

    //---- P2: LSTM layer 1; zero accumulators ----
    if (bid < 128) {
      stage_rows(h_new, hsB, tid);
      stage_rows(h_old + BHz, hsA, tid);
      __syncthreads();
      lstm_phase<false>(tid, bid, nullptr, nullptr, hsB, hsA,
                        Wih + (size_t)2048 * Hz, Whh + (size_t)2048 * Hz,
                        bih + 2048, bhh + 2048, s_part, s_bias, s_c + 128, h_new + BHz);
    } else if (bid == 128) {
      for (int u = tid; u < 2048; u += NTz) {
        __hip_atomic_store(&acc_sum[u], 0.f, __ATOMIC_RELAXED, __HIP_MEMORY_SCOPE_AGENT);
        __hip_atomic_store(&acc_max[u], 0ull, __ATOMIC_RELAXED, __HIP_MEMORY_SCOPE_AGENT);
      }
    }
    grid_barrier_rt(bar, bid, w12, x12, tA);

    if (tid == 0 && bid == 0) tA = rtclk();

    //---- P3: stage h2 (plain tile); register-resident matvec; softmax partials ----
    stage_plain(h_new + BHz, hsA, tid);
    __syncthreads();
    {
      const float* hb0 = hsA + kq;
      #pragma unroll 2
      for (int b = 0; b < 32; ++b) {
        const float* hb = hb0 + (b << 9);
        f32x2 acc2[4];
        #pragma unroll
        for (int r = 0; r < 4; ++r) { acc2[r].x = 0.f; acc2[r].y = 0.f; }
        #pragma unroll
        for (int p = 0; p < 16; ++p) {
          const int ca = (p < 8) ? p : p + 8;
          f32x2 hv;
          hv.x = hb[ca << 4];
          hv.y = hb[(ca + 8) << 4];
          #pragma unroll
          for (int r = 0; r < 4; ++r) acc2[r] += w2[r][p] * hv;
        }
        #pragma unroll
        for (int r = 0; r < 4; ++r) {
          float a = acc2[r].x + acc2[r].y;
          a += __shfl_xor(a, 1);
          a += __shfl_xor(a, 2);
          a += __shfl_xor(a, 4);
          a += __shfl_xor(a, 8);
          if (kq == 0) logits[b * 129 + (vg << 2) + r] = a + b_r[r];
        }
      }
    }
    __syncthreads();
    {
      const int b2 = tid & 31, ch = tid >> 5;   // 16 chunks x 8 vocab
      float m = -3.0e38f; int argv = 0; float s = 0.f;
      #pragma unroll
      for (int u = 0; u < 8; ++u) {
        int vl = ch * 8 + u;
        float x = logits[b2 * 129 + vl];
        s += expf(x);                            // offset-0 softmax: logits O(1), safe
        if (x > m) { m = x; argv = vl; }
      }
      pmax[ch * 32 + b2] = packlm(m, v0 + argv);
      psum[ch * 32 + b2] = s;
    }
    __syncthreads();
    if (tid < 32) {
      ull m = 0ull; float s = 0.f;
      #pragma unroll
      for (int ch = 0; ch < 16; ++ch) {
        ull x = pmax[ch * 32 + tid]; m = x > m ? x : m;
        s += psum[ch * 32 + tid];
      }
      atomicAdd(&acc_sum[(bid & 63) * Bz + tid], s);
      atomicMax(&acc_max[(bid & 63) * Bz + tid], m);
    }
    grid_barrier_rt(bar, bid, w3, x3, tA);
  }

  //---- epilogue: logp(T-1), hT, cT ----
  tok_reduce(tid, acc_sum, acc_max, redS, redM, s_logZ, s_tok);
  write_logp(tid, v0, Tz - 1, logits, s_logZ, out);
  if (bid >= 128 && bid < 144) {
    int f = (bid - 128) * 2048 + tid * 4;       // hT: 32768 floats from parity-0 buffer
    ull a = bp8(hbufs + f), b = bp8(hbufs + f + 2);
    *(ull*)(out + BTVz + f) = a;
    *(ull*)(out + BTVz + f + 2) = b;
  }
  if (bid < 128 && tid < 256) {
    int l = tid >> 7, hl = (tid >> 5) & 3, bb = tid & 31;
    out[BTVz + LBHz + (size_t)l * BHz + (size_t)bb * Hz + (bid << 2) + hl] =
        s_c[l * 128 + hl * 32 + bb];
  }
  if (bid == 0 && tid == 0) {
    ull* tw = (ull*)((char*)ws + WS_TIME);
    tw[0] = w12; tw[1] = x12; tw[2] = w3; tw[3] = x3;
  }
}

extern "C" void kernel_launch(void* const* d_in, const int* in_sizes, int n_in,
                              void* d_out, int out_size, void* d_ws, size_t ws_size,
                              hipStream_t stream) {
  (void)in_sizes; (void)n_in; (void)out_size; (void)ws_size;
  const float* enc  = (const float*)d_in[0];
  const float* emb  = (const float*)d_in[1];
  const float* Wih  = (const float*)d_in[2];
  const float* Whh  = (const float*)d_in[3];
  const float* bih  = (const float*)d_in[4];
  const float* bhh  = (const float*)d_in[5];
  const float* Wout = (const float*)d_in[6];
  const float* bout = (const float*)d_in[7];
  float* out = (float*)d_out;
  float* ws  = (float*)d_ws;
  const ull* tw = (const ull*)((char*)d_ws + WS_TIME);

  (void)hipFuncSetAttribute((const void*)rnn_decode,
                            hipFuncAttributeMaxDynamicSharedMemorySize, L_TOTAL);
  rnn_init<<<64, 512, 0, stream>>>(enc, ws);
  rnn_decode<<<Gz, NTz, L_TOTAL, stream>>>(emb, Wih, Whh, bih, bhh, Wout, bout, out, ws);
  k_marker<0><<<1, 64, 0, stream>>>(tw);   // dur*16 = P1+P2 work us
  k_marker<1><<<1, 64, 0, stream>>>(tw);   // dur*16 = P1+P2 barrier us
  k_marker<2><<<1, 64, 0, stream>>>(tw);   // dur*16 = P3 work us
  k_marker<3><<<1, 64, 0, stream>>>(tw);   // dur*16 = P3 barrier us
}